// Round 1
// baseline (97.039 us; speedup 1.0000x reference)
//
#include <hip/hip_runtime.h>

// FerroelectricBasisConv2d on MI355X.
// out[b,co,ho,wo] = out_bias[co] + sum_{cin,kk,i,j} f(x[b,cin,ho+i-1,wo+j-1]; p[co,cin,kk,i,j])
// f(x;p) = Ps*tanh(k*(x + Ec*(0.8 + 0.2*sigmoid(10*(x+Ec))))) + bias, times coef.
// Algebra: contribution = (Ps*c + b*c) - 2*Ps*c * 1/(exp2(G*shifted)+1), G = 2*log2(e)*k
//          sigmoid term s = 1/(exp2(C*(x+Ec))+1), C = -10*log2(e)
//          G*shifted = fma(0.2*G*Ec, s, fma(G, x, 0.8*G*Ec))
// Constant part summed once per block (per cout).

#define LOG2E 1.4426950408889634f

__global__ __launch_bounds__(256, 4) void ferro_kernel(
    const float* __restrict__ x, const float* __restrict__ k,
    const float* __restrict__ Ec, const float* __restrict__ Ps,
    const float* __restrict__ bias, const float* __restrict__ coef,
    const float* __restrict__ out_bias, float* __restrict__ out)
{
    // blockIdx.x = b*128 + co*4 + rb   (rb = 8-row strip index)
    const int bid = blockIdx.x;
    const int rb  = bid & 3;
    const int co  = (bid >> 2) & 31;
    const int b   = bid >> 7;
    const int tid = threadIdx.x;

    // params reordered to [cin][i*3+j][kk] so x is reused across kk
    __shared__ float4 p4[432];          // (CEc, G, Q=0.8*G*Ec, R=0.2*G*Ec)
    __shared__ float  pA[432];          // -2*Ps*c
    __shared__ float  xs[16 * 10 * 34]; // padded x strip [cin][row][col]
    __shared__ float  red[4];
    __shared__ float  constco_sh;

    // ---- stage params (co-slice of 432 tuples) ----
    const int pbase = co * 432;
    float cpart = 0.f;
    for (int s = tid; s < 432; s += 256) {
        float kv = k[pbase + s];
        float ev = Ec[pbase + s];
        float pv = Ps[pbase + s];
        float bv = bias[pbase + s];
        float cv = coef[pbase + s];
        float G  = 2.f * LOG2E * kv;
        float4 v;
        v.x = -10.f * LOG2E * ev;  // CEc
        v.y = G;
        v.z = 0.8f * G * ev;       // Q
        v.w = 0.2f * G * ev;       // R
        // src order: s = cin*27 + kk*9 + (i*3+j)  ->  dst = cin*27 + (i*3+j)*3 + kk
        int cin = s / 27;
        int r   = s - cin * 27;
        int kk  = r / 9;
        int ij  = r - kk * 9;
        int dst = cin * 27 + ij * 3 + kk;
        p4[dst] = v;
        pA[dst] = -2.f * pv * cv;
        cpart += (pv + bv) * cv;   // Ps*c + b*c
    }

    // ---- stage x: rows r0-1..r0+8, cols -1..32, zero padded ----
    const int r0 = rb * 8;
    const float* xb = x + b * (16 * 32 * 32);
    for (int idx = tid; idx < 16 * 10 * 34; idx += 256) {
        int cin  = idx / 340;
        int rem  = idx - cin * 340;
        int row  = rem / 34;
        int colp = rem - row * 34;
        int gr = r0 + row - 1;
        int gc = colp - 1;
        float v = 0.f;
        if ((unsigned)gr < 32u && (unsigned)gc < 32u)
            v = xb[(cin * 32 + gr) * 32 + gc];
        xs[idx] = v;
    }

    // ---- block-reduce the per-cout constant ----
    #pragma unroll
    for (int off = 32; off > 0; off >>= 1)
        cpart += __shfl_down(cpart, off, 64);
    if ((tid & 63) == 0) red[tid >> 6] = cpart;
    __syncthreads();
    if (tid == 0) constco_sh = red[0] + red[1] + red[2] + red[3];
    __syncthreads();

    // ---- eval loop: 1 output pixel per thread ----
    const int lr  = tid >> 5;   // 0..7
    const int col = tid & 31;
    const float Cx = -10.f * LOG2E;
    float acc = 0.f;

    #pragma unroll 2
    for (int cin = 0; cin < 16; ++cin) {
        const float*  xr = &xs[cin * 340 + lr * 34 + col];
        const float4* pp = &p4[cin * 27];
        const float*  aa = &pA[cin * 27];
        #pragma unroll
        for (int i = 0; i < 3; ++i) {
            #pragma unroll
            for (int j = 0; j < 3; ++j) {
                float xv = xr[i * 34 + j];
                float xC = Cx * xv;
                #pragma unroll
                for (int kk = 0; kk < 3; ++kk) {
                    int t = (i * 3 + j) * 3 + kk;
                    float4 v  = pp[t];
                    float  a2 = aa[t];
                    float e1 = __builtin_amdgcn_exp2f(xC + v.x);
                    float s  = __builtin_amdgcn_rcpf(e1 + 1.f);
                    float arg2 = fmaf(v.w, s, fmaf(v.y, xv, v.z));
                    float e2 = __builtin_amdgcn_exp2f(arg2);
                    float u  = __builtin_amdgcn_rcpf(e2 + 1.f);
                    acc = fmaf(a2, u, acc);
                }
            }
        }
    }

    float ob = out_bias[co];
    out[((b * 32 + co) * 32 + (r0 + lr)) * 32 + col] = constco_sh + acc + ob;
}

extern "C" void kernel_launch(void* const* d_in, const int* in_sizes, int n_in,
                              void* d_out, int out_size, void* d_ws, size_t ws_size,
                              hipStream_t stream) {
    const float* x        = (const float*)d_in[0];
    const float* k        = (const float*)d_in[1];
    const float* Ec       = (const float*)d_in[2];
    const float* Ps       = (const float*)d_in[3];
    const float* bias     = (const float*)d_in[4];
    const float* coef     = (const float*)d_in[5];
    const float* out_bias = (const float*)d_in[6];
    float* out = (float*)d_out;

    // grid: B(4) * Cout(32) * row-strips(4) = 512 blocks of 256 threads
    ferro_kernel<<<dim3(512), dim3(256), 0, stream>>>(
        x, k, Ec, Ps, bias, coef, out_bias, out);
}

// Round 2
// 93.026 us; speedup vs baseline: 1.0431x; 1.0431x over previous
//
#include <hip/hip_runtime.h>

// FerroelectricBasisConv2d on MI355X — round 2.
// Math (verified in R1, absmax 0.125): per tuple p=(k,Ec,Ps,b,c):
//   contribution = (Ps*c + b*c) - 2*Ps*c * rcp(exp2(G*shifted)+1),  G = 2*log2e*k
//   s = rcp(exp2(CEc + Cx*x)+1),  CEc = -10*log2e*Ec, Cx = -10*log2e
//   G*shifted = fma(R, s, fma(G, x, Q)),  Q = 0.8*G*Ec, R = 0.2*G*Ec
// Prep kernel: transforms params into ws, reduces the constant part per cout,
// initializes out = out_bias + const. Main kernel: 1024 blocks (4/CU), each
// handles (b, co, 8-row strip, cin-half) and atomicAdds its partial sum.

#define LOG2E 1.4426950408889634f

struct WsLayout {
    // float4 p4[32*432]  at byte 0        (221184 B)
    // float  pA[32*432]  at byte 221184   (55296 B)
};

__global__ __launch_bounds__(512) void ferro_prep(
    const float* __restrict__ k, const float* __restrict__ Ec,
    const float* __restrict__ Ps, const float* __restrict__ bias,
    const float* __restrict__ coef, const float* __restrict__ out_bias,
    float4* __restrict__ p4g, float* __restrict__ pAg,
    float* __restrict__ out)
{
    const int co  = blockIdx.x;       // 0..31
    const int tid = threadIdx.x;      // 0..511
    __shared__ float red[8];
    __shared__ float val_sh;

    const int pbase = co * 432;
    float cpart = 0.f;
    if (tid < 432) {
        float kv = k[pbase + tid];
        float ev = Ec[pbase + tid];
        float pv = Ps[pbase + tid];
        float bv = bias[pbase + tid];
        float cv = coef[pbase + tid];
        float G  = 2.f * LOG2E * kv;
        float4 v;
        v.x = -10.f * LOG2E * ev;  // CEc
        v.y = G;
        v.z = 0.8f * G * ev;       // Q
        v.w = 0.2f * G * ev;       // R
        // src s = cin*27 + kk*9 + ij  ->  dst = cin*27 + ij*3 + kk
        int cin = tid / 27;
        int r   = tid - cin * 27;
        int kk  = r / 9;
        int ij  = r - kk * 9;
        int dst = pbase + cin * 27 + ij * 3 + kk;
        p4g[dst] = v;
        pAg[dst] = -2.f * pv * cv;
        cpart = (pv + bv) * cv;
    }
    #pragma unroll
    for (int off = 32; off > 0; off >>= 1)
        cpart += __shfl_down(cpart, off, 64);
    if ((tid & 63) == 0) red[tid >> 6] = cpart;
    __syncthreads();
    if (tid == 0) {
        float t = 0.f;
        #pragma unroll
        for (int w = 0; w < 8; ++w) t += red[w];
        val_sh = t + out_bias[co];
    }
    __syncthreads();
    const float val = val_sh;
    // init out[:, co, :, :] = val   (4 batches x 1024 pixels)
    for (int i = tid; i < 4096; i += 512) {
        int bI  = i >> 10;
        int pix = i & 1023;
        out[(bI * 32 + co) * 1024 + pix] = val;
    }
}

__global__ __launch_bounds__(256, 4) void ferro_main(
    const float* __restrict__ x,
    const float4* __restrict__ p4g, const float* __restrict__ pAg,
    float* __restrict__ out)
{
    // bid = b*256 + co*8 + rb*2 + cinh
    const int bid  = blockIdx.x;
    const int cinh = bid & 1;
    const int rb   = (bid >> 1) & 3;
    const int co   = (bid >> 3) & 31;
    const int b    = bid >> 8;
    const int tid  = threadIdx.x;

    __shared__ float4 p4s[216];          // [cin8][ij][kk]
    __shared__ float  pAs[216];
    __shared__ float  xs[8 * 10 * 34];   // [cin8][row10][col34]

    // ---- stage transformed params (contiguous slice) ----
    const int poff = co * 432 + cinh * 216;
    if (tid < 216) {
        p4s[tid] = p4g[poff + tid];
        pAs[tid] = pAg[poff + tid];
    }

    // ---- stage x strip: cins cin0..cin0+7, rows r0-1..r0+8, cols -1..32 ----
    const int r0   = rb * 8;
    const int cin0 = cinh * 8;
    const float* xb = x + (b * 16 + cin0) * 1024;
    for (int idx = tid; idx < 8 * 340; idx += 256) {
        int cin  = idx / 340;
        int rem  = idx - cin * 340;
        int row  = rem / 34;
        int colp = rem - row * 34;
        int gr = r0 + row - 1;
        int gc = colp - 1;
        float v = 0.f;
        if ((unsigned)gr < 32u && (unsigned)gc < 32u)
            v = xb[(cin * 32 + gr) * 32 + gc];
        xs[idx] = v;
    }
    __syncthreads();

    // ---- eval: 1 pixel/thread, 8 cins x 27 tuples ----
    const int lr  = tid >> 5;   // 0..7
    const int col = tid & 31;
    const float Cx = -10.f * LOG2E;
    float acc0 = 0.f, acc1 = 0.f;

    #pragma unroll 1
    for (int cin = 0; cin < 8; ++cin) {
        const float*  xr = &xs[cin * 340 + lr * 34 + col];
        const float4* pp = &p4s[cin * 27];
        const float*  aa = &pAs[cin * 27];
        #pragma unroll
        for (int i = 0; i < 3; ++i) {
            #pragma unroll
            for (int j = 0; j < 3; ++j) {
                float xv = xr[i * 34 + j];
                float xC = Cx * xv;
                #pragma unroll
                for (int kk = 0; kk < 3; ++kk) {
                    int t = (i * 3 + j) * 3 + kk;
                    float4 v  = pp[t];
                    float  a2 = aa[t];
                    float e1 = __builtin_amdgcn_exp2f(xC + v.x);
                    float s  = __builtin_amdgcn_rcpf(e1 + 1.f);
                    float arg2 = fmaf(v.w, s, fmaf(v.y, xv, v.z));
                    float e2 = __builtin_amdgcn_exp2f(arg2);
                    float u  = __builtin_amdgcn_rcpf(e2 + 1.f);
                    if (kk & 1) acc1 = fmaf(a2, u, acc1);
                    else        acc0 = fmaf(a2, u, acc0);
                }
            }
        }
    }

    atomicAdd(&out[((b * 32 + co) * 32 + (r0 + lr)) * 32 + col], acc0 + acc1);
}

extern "C" void kernel_launch(void* const* d_in, const int* in_sizes, int n_in,
                              void* d_out, int out_size, void* d_ws, size_t ws_size,
                              hipStream_t stream) {
    const float* x        = (const float*)d_in[0];
    const float* k        = (const float*)d_in[1];
    const float* Ec       = (const float*)d_in[2];
    const float* Ps       = (const float*)d_in[3];
    const float* bias     = (const float*)d_in[4];
    const float* coef     = (const float*)d_in[5];
    const float* out_bias = (const float*)d_in[6];
    float* out = (float*)d_out;

    float4* p4g = (float4*)d_ws;                          // 32*432 float4
    float*  pAg = (float*)((char*)d_ws + 32 * 432 * 16);  // 32*432 float

    ferro_prep<<<dim3(32), dim3(512), 0, stream>>>(
        k, Ec, Ps, bias, coef, out_bias, p4g, pAg, out);
    ferro_main<<<dim3(1024), dim3(256), 0, stream>>>(x, p4g, pAg, out);
}